// Round 2
// baseline (120.286 us; speedup 1.0000x reference)
//
#include <hip/hip_runtime.h>
#include <hip/hip_bf16.h>

#define D 512
#define TILE 128
#define BK 64
#define LDK (BK + 8)   // +8 bf16 pad -> 144B row stride -> 2-way LDS conflicts (free)

typedef __attribute__((ext_vector_type(8))) short bf16x8;
typedef __attribute__((ext_vector_type(4))) float f32x4;

__device__ inline unsigned short f2bf(float x) {
    __hip_bfloat16 h = __float2bfloat16(x);
    return __builtin_bit_cast(unsigned short, h);
}

// Kernel A: row L2-norms, normalized bf16 matrix Yn[2N][D], pos[i]=exp(2*cos(y_i,yh_i))
__global__ __launch_bounds__(128) void prep_kernel(const float* __restrict__ y,
                                                   const float* __restrict__ yh,
                                                   unsigned short* __restrict__ Yn,
                                                   float* __restrict__ pos, int N) {
    const int i = blockIdx.x;
    const int t = threadIdx.x;  // 0..127, each owns one float4 (4 elems) of the 512
    const float4 a = ((const float4*)(y + (size_t)i * D))[t];
    const float4 b = ((const float4*)(yh + (size_t)i * D))[t];
    float sy = a.x*a.x + a.y*a.y + a.z*a.z + a.w*a.w;
    float sh = b.x*b.x + b.y*b.y + b.z*b.z + b.w*b.w;
    float sd = a.x*b.x + a.y*b.y + a.z*b.z + a.w*b.w;
    #pragma unroll
    for (int o = 32; o > 0; o >>= 1) {
        sy += __shfl_xor(sy, o);
        sh += __shfl_xor(sh, o);
        sd += __shfl_xor(sd, o);
    }
    __shared__ float red[3][2];
    const int wv = t >> 6;
    if ((t & 63) == 0) { red[0][wv] = sy; red[1][wv] = sh; red[2][wv] = sd; }
    __syncthreads();
    sy = red[0][0] + red[0][1];
    sh = red[1][0] + red[1][1];
    sd = red[2][0] + red[2][1];
    const float ny = sqrtf(sy), nh = sqrtf(sh);
    const float ry = 1.f / fmaxf(ny, 1e-12f), rh = 1.f / fmaxf(nh, 1e-12f);
    ushort4 oa, ob;
    oa.x = f2bf(a.x * ry); oa.y = f2bf(a.y * ry); oa.z = f2bf(a.z * ry); oa.w = f2bf(a.w * ry);
    ob.x = f2bf(b.x * rh); ob.y = f2bf(b.y * rh); ob.z = f2bf(b.z * rh); ob.w = f2bf(b.w * rh);
    ((ushort4*)(Yn + (size_t)i * D))[t] = oa;
    ((ushort4*)(Yn + (size_t)(i + N) * D))[t] = ob;
    if (t == 0) {
        const float cs = sd / (fmaxf(ny, 1e-8f) * fmaxf(nh, 1e-8f));
        pos[i] = __expf(2.f * cs);
    }
}

// Kernel B: neg[i] += sum_j exp(2 * Yn_i . Yn_j), diagonal masked.
// Upper-triangle blocks only (bx>=by); off-diagonal blocks also add the mirrored
// column sums (S is symmetric), halving the MFMA work.
__global__ __launch_bounds__(256) void simgemm_kernel(const unsigned short* __restrict__ Yn,
                                                      float* __restrict__ neg) {
    const int bx = blockIdx.x, by = blockIdx.y;
    if (bx < by) return;
    __shared__ unsigned short As[TILE][LDK];
    __shared__ unsigned short Bs[TILE][LDK];
    const int tid = threadIdx.x;
    const int lane = tid & 63;
    const int w = tid >> 6;
    const int wm = (w >> 1) * 64, wn = (w & 1) * 64;   // wave's 64x64 quadrant
    const int fr = lane & 15;    // A-row / B-col within 16x16 frag
    const int fq = lane >> 4;    // k-chunk (inputs) / row-quad (output)
    const int rowA0 = by * TILE, rowB0 = bx * TILE;

    f32x4 acc[4][4] = {};

    const int sr = tid >> 3;          // staging row 0..31
    const int kx = (tid & 7) * 8;     // staging k-offset (elements)

    for (int k0 = 0; k0 < D; k0 += BK) {
        #pragma unroll
        for (int p = 0; p < 4; ++p) {
            const int row = sr + p * 32;
            *(uint4*)&As[row][kx] = *(const uint4*)&Yn[(size_t)(rowA0 + row) * D + k0 + kx];
            *(uint4*)&Bs[row][kx] = *(const uint4*)&Yn[(size_t)(rowB0 + row) * D + k0 + kx];
        }
        __syncthreads();
        #pragma unroll
        for (int kk = 0; kk < BK; kk += 32) {
            bf16x8 af[4], bfr[4];
            const int koff = kk + fq * 8;
            #pragma unroll
            for (int m = 0; m < 4; ++m) af[m] = *(bf16x8*)&As[wm + m * 16 + fr][koff];
            #pragma unroll
            for (int n = 0; n < 4; ++n) bfr[n] = *(bf16x8*)&Bs[wn + n * 16 + fr][koff];
            #pragma unroll
            for (int m = 0; m < 4; ++m)
                #pragma unroll
                for (int n = 0; n < 4; ++n)
                    acc[m][n] = __builtin_amdgcn_mfma_f32_16x16x32_bf16(af[m], bfr[n], acc[m][n], 0, 0, 0);
        }
        __syncthreads();
    }

    const bool diagblk = (bx == by);
    // exp transform in-place (+ exact diagonal mask)
    #pragma unroll
    for (int m = 0; m < 4; ++m)
        #pragma unroll
        for (int n = 0; n < 4; ++n)
            #pragma unroll
            for (int r = 0; r < 4; ++r) {
                const float e = __expf(2.f * acc[m][n][r]);
                const bool diag = diagblk && (wm + m * 16 + fq * 4 + r) == (wn + n * 16 + fr);
                acc[m][n][r] = diag ? 0.f : e;
            }
    // row sums: reduce over n-frags then over the 16 col-lanes
    #pragma unroll
    for (int m = 0; m < 4; ++m)
        #pragma unroll
        for (int r = 0; r < 4; ++r) {
            float v = acc[m][0][r] + acc[m][1][r] + acc[m][2][r] + acc[m][3][r];
            v += __shfl_xor(v, 1);
            v += __shfl_xor(v, 2);
            v += __shfl_xor(v, 4);
            v += __shfl_xor(v, 8);
            if (fr == 0) atomicAdd(&neg[rowA0 + wm + m * 16 + fq * 4 + r], v);
        }
    // mirrored column sums for off-diagonal blocks
    if (!diagblk) {
        #pragma unroll
        for (int n = 0; n < 4; ++n) {
            float v = 0.f;
            #pragma unroll
            for (int m = 0; m < 4; ++m)
                #pragma unroll
                for (int r = 0; r < 4; ++r) v += acc[m][n][r];
            v += __shfl_xor(v, 16);
            v += __shfl_xor(v, 32);
            if (fq == 0) atomicAdd(&neg[rowB0 + wn + n * 16 + fr], v);
        }
    }
}

// Kernel C: loss = log(2N) - log( sum_i pos[i] * (1/neg[i] + 1/neg[i+N]) )
__global__ __launch_bounds__(256) void finish_kernel(const float* __restrict__ pos,
                                                     const float* __restrict__ neg,
                                                     float* __restrict__ out, int N) {
    float s = 0.f;
    for (int i = threadIdx.x; i < N; i += 256)
        s += pos[i] * (1.f / neg[i] + 1.f / neg[i + N]);
    #pragma unroll
    for (int o = 32; o > 0; o >>= 1) s += __shfl_xor(s, o);
    __shared__ float red[4];
    const int wv = threadIdx.x >> 6;
    if ((threadIdx.x & 63) == 0) red[wv] = s;
    __syncthreads();
    if (threadIdx.x == 0) {
        const float tot = red[0] + red[1] + red[2] + red[3];
        out[0] = logf(2.f * (float)N) - logf(tot);
    }
}

extern "C" void kernel_launch(void* const* d_in, const int* in_sizes, int n_in,
                              void* d_out, int out_size, void* d_ws, size_t ws_size,
                              hipStream_t stream) {
    const float* y  = (const float*)d_in[0];
    const float* yh = (const float*)d_in[1];
    const int N  = in_sizes[0] / D;   // 4096
    const int N2 = 2 * N;             // 8192

    unsigned short* Yn = (unsigned short*)d_ws;                 // [2N][D] bf16, 8 MB
    const size_t yn_bytes = (size_t)N2 * D * sizeof(unsigned short);
    float* neg = (float*)((char*)d_ws + yn_bytes);              // [2N]
    float* pos = neg + N2;                                      // [N]
    float* out = (float*)d_out;

    hipMemsetAsync(neg, 0, N2 * sizeof(float), stream);
    prep_kernel<<<N, 128, 0, stream>>>(y, yh, Yn, pos, N);
    const int nt = N2 / TILE;
    simgemm_kernel<<<dim3(nt, nt), 256, 0, stream>>>(Yn, neg);
    finish_kernel<<<1, 256, 0, stream>>>(pos, neg, out, N);
}

// Round 3
// 101.466 us; speedup vs baseline: 1.1855x; 1.1855x over previous
//
#include <hip/hip_runtime.h>
#include <hip/hip_bf16.h>

#define D 512
#define TILE 128
#define BK 64
#define NT 64           // 8192 / TILE
#define NBLK (NT*(NT+1)/2)   // 2080 triangular blocks

typedef __attribute__((ext_vector_type(8))) short bf16x8;
typedef __attribute__((ext_vector_type(4))) float f32x4;

__device__ inline unsigned short f2bf(float x) {
    __hip_bfloat16 h = __float2bfloat16(x);
    return __builtin_bit_cast(unsigned short, h);
}

// async global -> LDS, 16B per lane; LDS dest is wave-uniform base + lane*16
__device__ inline void gload16(const unsigned short* g, unsigned short* l) {
    __builtin_amdgcn_global_load_lds(
        (const __attribute__((address_space(1))) unsigned int*)g,
        (__attribute__((address_space(3))) unsigned int*)l,
        16, 0, 0);
}

// Kernel A: row L2-norms, normalized bf16 matrix Yn[2N][D], pos[i]=exp(2*cos(y_i,yh_i))
__global__ __launch_bounds__(128) void prep_kernel(const float* __restrict__ y,
                                                   const float* __restrict__ yh,
                                                   unsigned short* __restrict__ Yn,
                                                   float* __restrict__ pos, int N) {
    const int i = blockIdx.x;
    const int t = threadIdx.x;  // 0..127, each owns one float4 (4 elems) of the 512
    const float4 a = ((const float4*)(y + (size_t)i * D))[t];
    const float4 b = ((const float4*)(yh + (size_t)i * D))[t];
    float sy = a.x*a.x + a.y*a.y + a.z*a.z + a.w*a.w;
    float sh = b.x*b.x + b.y*b.y + b.z*b.z + b.w*b.w;
    float sd = a.x*b.x + a.y*b.y + a.z*b.z + a.w*b.w;
    #pragma unroll
    for (int o = 32; o > 0; o >>= 1) {
        sy += __shfl_xor(sy, o);
        sh += __shfl_xor(sh, o);
        sd += __shfl_xor(sd, o);
    }
    __shared__ float red[3][2];
    const int wv = t >> 6;
    if ((t & 63) == 0) { red[0][wv] = sy; red[1][wv] = sh; red[2][wv] = sd; }
    __syncthreads();
    sy = red[0][0] + red[0][1];
    sh = red[1][0] + red[1][1];
    sd = red[2][0] + red[2][1];
    const float ny = sqrtf(sy), nh = sqrtf(sh);
    const float ry = 1.f / fmaxf(ny, 1e-12f), rh = 1.f / fmaxf(nh, 1e-12f);
    ushort4 oa, ob;
    oa.x = f2bf(a.x * ry); oa.y = f2bf(a.y * ry); oa.z = f2bf(a.z * ry); oa.w = f2bf(a.w * ry);
    ob.x = f2bf(b.x * rh); ob.y = f2bf(b.y * rh); ob.z = f2bf(b.z * rh); ob.w = f2bf(b.w * rh);
    ((ushort4*)(Yn + (size_t)i * D))[t] = oa;
    ((ushort4*)(Yn + (size_t)(i + N) * D))[t] = ob;
    if (t == 0) {
        const float cs = sd / (fmaxf(ny, 1e-8f) * fmaxf(nh, 1e-8f));
        pos[i] = __expf(2.f * cs);
    }
}

// Kernel B: neg[i] += sum_j exp(2 * Yn_i . Yn_j), diagonal masked.
// 1D triangular grid: block t -> (bx >= by). Off-diagonal blocks also add the
// mirrored column sums (S symmetric), ~halving MFMA work.
// Staging: global_load_lds width-16 into linear [128][64] LDS (m97 structure).
__global__ __launch_bounds__(256) void simgemm_kernel(const unsigned short* __restrict__ Yn,
                                                      float* __restrict__ neg) {
    // triangular decode: t = bx*(bx+1)/2 + by, by <= bx
    const int t = blockIdx.x;
    int bx = (int)((sqrtf(8.f * (float)t + 1.f) - 1.f) * 0.5f);
    while ((bx + 1) * (bx + 2) / 2 <= t) ++bx;
    while (bx * (bx + 1) / 2 > t) --bx;
    const int by = t - bx * (bx + 1) / 2;

    __shared__ unsigned short As[TILE * BK];   // linear [128][64], row-major
    __shared__ unsigned short Bs[TILE * BK];
    const int tid = threadIdx.x;
    const int lane = tid & 63;
    const int w = tid >> 6;
    const int wm = (w >> 1) * 64, wn = (w & 1) * 64;   // wave's 64x64 quadrant
    const int fr = lane & 15;    // A-row / B-col within 16x16 frag
    const int fq = lane >> 4;    // k-chunk (inputs) / row-quad (output)
    const int rowA0 = by * TILE, rowB0 = bx * TILE;

    f32x4 acc[4][4] = {};

    // staging geometry: chunk c = p*256 + tid covers row=c/8, col8=(c%8)*8
    const int srow = tid >> 3;           // 0..31 (row within 32-row stripe)
    const int scol = (tid & 7) * 8;      // k-offset in elements
    const int ldsoff = (tid >> 6) * 512; // wave-uniform element offset within stripe-issue

    for (int k0 = 0; k0 < D; k0 += BK) {
        #pragma unroll
        for (int p = 0; p < 4; ++p) {
            const int row = p * 32 + srow;
            gload16(&Yn[(size_t)(rowA0 + row) * D + k0 + scol], &As[p * 2048 + ldsoff]);
            gload16(&Yn[(size_t)(rowB0 + row) * D + k0 + scol], &Bs[p * 2048 + ldsoff]);
        }
        __syncthreads();   // drains vmcnt + lgkm, barrier
        #pragma unroll
        for (int kk = 0; kk < BK; kk += 32) {
            bf16x8 af[4], bfr[4];
            const int koff = kk + fq * 8;
            #pragma unroll
            for (int m = 0; m < 4; ++m) af[m] = *(bf16x8*)&As[(wm + m * 16 + fr) * BK + koff];
            #pragma unroll
            for (int n = 0; n < 4; ++n) bfr[n] = *(bf16x8*)&Bs[(wn + n * 16 + fr) * BK + koff];
            #pragma unroll
            for (int m = 0; m < 4; ++m)
                #pragma unroll
                for (int n = 0; n < 4; ++n)
                    acc[m][n] = __builtin_amdgcn_mfma_f32_16x16x32_bf16(af[m], bfr[n], acc[m][n], 0, 0, 0);
        }
        __syncthreads();
    }

    const bool diagblk = (bx == by);
    // exp transform in-place (+ exact diagonal mask)
    #pragma unroll
    for (int m = 0; m < 4; ++m)
        #pragma unroll
        for (int n = 0; n < 4; ++n)
            #pragma unroll
            for (int r = 0; r < 4; ++r) {
                const float e = __expf(2.f * acc[m][n][r]);
                const bool diag = diagblk && (wm + m * 16 + fq * 4 + r) == (wn + n * 16 + fr);
                acc[m][n][r] = diag ? 0.f : e;
            }
    // row sums: reduce over n-frags then over the 16 col-lanes
    #pragma unroll
    for (int m = 0; m < 4; ++m)
        #pragma unroll
        for (int r = 0; r < 4; ++r) {
            float v = acc[m][0][r] + acc[m][1][r] + acc[m][2][r] + acc[m][3][r];
            v += __shfl_xor(v, 1);
            v += __shfl_xor(v, 2);
            v += __shfl_xor(v, 4);
            v += __shfl_xor(v, 8);
            if (fr == 0) atomicAdd(&neg[rowA0 + wm + m * 16 + fq * 4 + r], v);
        }
    // mirrored column sums for off-diagonal blocks
    if (!diagblk) {
        #pragma unroll
        for (int n = 0; n < 4; ++n) {
            float v = 0.f;
            #pragma unroll
            for (int m = 0; m < 4; ++m)
                #pragma unroll
                for (int r = 0; r < 4; ++r) v += acc[m][n][r];
            v += __shfl_xor(v, 16);
            v += __shfl_xor(v, 32);
            if (fq == 0) atomicAdd(&neg[rowB0 + wn + n * 16 + fr], v);
        }
    }
}

// Kernel C: loss = log(2N) - log( sum_i pos[i] * (1/neg[i] + 1/neg[i+N]) )
__global__ __launch_bounds__(256) void finish_kernel(const float* __restrict__ pos,
                                                     const float* __restrict__ neg,
                                                     float* __restrict__ out, int N) {
    float s = 0.f;
    for (int i = threadIdx.x; i < N; i += 256)
        s += pos[i] * (1.f / neg[i] + 1.f / neg[i + N]);
    #pragma unroll
    for (int o = 32; o > 0; o >>= 1) s += __shfl_xor(s, o);
    __shared__ float red[4];
    const int wv = threadIdx.x >> 6;
    if ((threadIdx.x & 63) == 0) red[wv] = s;
    __syncthreads();
    if (threadIdx.x == 0) {
        const float tot = red[0] + red[1] + red[2] + red[3];
        out[0] = logf(2.f * (float)N) - logf(tot);
    }
}

extern "C" void kernel_launch(void* const* d_in, const int* in_sizes, int n_in,
                              void* d_out, int out_size, void* d_ws, size_t ws_size,
                              hipStream_t stream) {
    const float* y  = (const float*)d_in[0];
    const float* yh = (const float*)d_in[1];
    const int N  = in_sizes[0] / D;   // 4096
    const int N2 = 2 * N;             // 8192

    unsigned short* Yn = (unsigned short*)d_ws;                 // [2N][D] bf16, 8 MB
    const size_t yn_bytes = (size_t)N2 * D * sizeof(unsigned short);
    float* neg = (float*)((char*)d_ws + yn_bytes);              // [2N]
    float* pos = neg + N2;                                      // [N]
    float* out = (float*)d_out;

    hipMemsetAsync(neg, 0, N2 * sizeof(float), stream);
    prep_kernel<<<N, 128, 0, stream>>>(y, yh, Yn, pos, N);
    simgemm_kernel<<<NBLK, 256, 0, stream>>>(Yn, neg);
    finish_kernel<<<1, 256, 0, stream>>>(pos, neg, out, N);
}

// Round 5
// 82.799 us; speedup vs baseline: 1.4528x; 1.2254x over previous
//
#include <hip/hip_runtime.h>
#include <hip/hip_bf16.h>

#define D 512
#define TILE 128
#define BK 64
#define NT 64                 // 8192 / TILE
#define NBLK (NT*(NT+1)/2)    // 2080 triangular blocks

typedef __attribute__((ext_vector_type(8))) short bf16x8;
typedef __attribute__((ext_vector_type(4))) float f32x4;

__device__ inline unsigned short f2bf(float x) {
    __hip_bfloat16 h = __float2bfloat16(x);
    return __builtin_bit_cast(unsigned short, h);
}

// async global -> LDS, 16B per lane; LDS dest is wave-uniform base + lane*16
__device__ inline void gload16(const unsigned short* g, unsigned short* l) {
    __builtin_amdgcn_global_load_lds(
        (const __attribute__((address_space(1))) unsigned int*)g,
        (__attribute__((address_space(3))) unsigned int*)l,
        16, 0, 0);
}

// Kernel A: row L2-norms, normalized bf16 matrix Yn[2N][D], pos[i]=exp(2*cos(y_i,yh_i))
__global__ __launch_bounds__(128) void prep_kernel(const float* __restrict__ y,
                                                   const float* __restrict__ yh,
                                                   unsigned short* __restrict__ Yn,
                                                   float* __restrict__ pos, int N) {
    const int i = blockIdx.x;
    const int t = threadIdx.x;  // 0..127, each owns one float4 (4 elems) of the 512
    const float4 a = ((const float4*)(y + (size_t)i * D))[t];
    const float4 b = ((const float4*)(yh + (size_t)i * D))[t];
    float sy = a.x*a.x + a.y*a.y + a.z*a.z + a.w*a.w;
    float sh = b.x*b.x + b.y*b.y + b.z*b.z + b.w*b.w;
    float sd = a.x*b.x + a.y*b.y + a.z*b.z + a.w*b.w;
    #pragma unroll
    for (int o = 32; o > 0; o >>= 1) {
        sy += __shfl_xor(sy, o);
        sh += __shfl_xor(sh, o);
        sd += __shfl_xor(sd, o);
    }
    __shared__ float red[3][2];
    const int wv = t >> 6;
    if ((t & 63) == 0) { red[0][wv] = sy; red[1][wv] = sh; red[2][wv] = sd; }
    __syncthreads();
    sy = red[0][0] + red[0][1];
    sh = red[1][0] + red[1][1];
    sd = red[2][0] + red[2][1];
    const float ny = sqrtf(sy), nh = sqrtf(sh);
    const float ry = 1.f / fmaxf(ny, 1e-12f), rh = 1.f / fmaxf(nh, 1e-12f);
    ushort4 oa, ob;
    oa.x = f2bf(a.x * ry); oa.y = f2bf(a.y * ry); oa.z = f2bf(a.z * ry); oa.w = f2bf(a.w * ry);
    ob.x = f2bf(b.x * rh); ob.y = f2bf(b.y * rh); ob.z = f2bf(b.z * rh); ob.w = f2bf(b.w * rh);
    ((ushort4*)(Yn + (size_t)i * D))[t] = oa;
    ((ushort4*)(Yn + (size_t)(i + N) * D))[t] = ob;
    if (t == 0) {
        const float cs = sd / (fmaxf(ny, 1e-8f) * fmaxf(nh, 1e-8f));
        pos[i] = __expf(2.f * cs);
    }
}

// Kernel B: neg[i] += sum_j exp(2 * Yn_i . Yn_j), diagonal masked.
// 1D triangular grid (bx >= by); off-diagonal blocks also add mirrored column
// sums (S symmetric). Staging: global_load_lds width-16, linear LDS dest,
// XOR-swizzled global SOURCE (chunk ^= row&7 per 16B unit) + same XOR on the
// ds_read side -> 16-way bank conflict becomes 2-way (free).
// Double-buffered LDS, prefetch-next-before-compute, one barrier per K-step.
__global__ __launch_bounds__(256) void simgemm_kernel(const unsigned short* __restrict__ Yn,
                                                      float* __restrict__ neg) {
    // triangular decode: t = bx*(bx+1)/2 + by, by <= bx
    const int t = blockIdx.x;
    int bx = (int)((sqrtf(8.f * (float)t + 1.f) - 1.f) * 0.5f);
    while ((bx + 1) * (bx + 2) / 2 <= t) ++bx;
    while (bx * (bx + 1) / 2 > t) --bx;
    const int by = t - bx * (bx + 1) / 2;

    __shared__ unsigned short As[2][TILE * BK];   // [128][64] rows = 8 x 16B chunks
    __shared__ unsigned short Bs[2][TILE * BK];
    const int tid = threadIdx.x;
    const int lane = tid & 63;
    const int w = tid >> 6;
    const int wm = (w >> 1) * 64, wn = (w & 1) * 64;   // wave's 64x64 quadrant
    const int fr = lane & 15;    // A-row / B-col within 16x16 frag
    const int fq = lane >> 4;    // k-chunk (inputs) / row-quad (output)
    const int rowA0 = by * TILE, rowB0 = bx * TILE;

    f32x4 acc[4][4] = {};

    // staging: thread covers global (row = p*32 + (tid>>3), 16B-chunk swizzled)
    const int srow = tid >> 3;                                  // 0..31
    const int scol = (((tid & 7) ^ ((tid >> 3) & 7)) << 3);     // pre-swizzled source col (elems)
    const int ldsoff = w * 512;                                 // wave-uniform elem offset

    const unsigned short* gA = Yn + (size_t)(rowA0 + srow) * D + scol;
    const unsigned short* gB = Yn + (size_t)(rowB0 + srow) * D + scol;

    auto STAGE = [&](int buf, int k0) {
        #pragma unroll
        for (int p = 0; p < 4; ++p) {
            gload16(gA + (size_t)p * 32 * D + k0, &As[buf][p * 2048 + ldsoff]);
            gload16(gB + (size_t)p * 32 * D + k0, &Bs[buf][p * 2048 + ldsoff]);
        }
    };

    STAGE(0, 0);
    __syncthreads();               // drain prologue stage
    int cur = 0;
    #pragma unroll
    for (int kt = 0; kt < D / BK; ++kt) {
        if (kt < D / BK - 1) STAGE(cur ^ 1, (kt + 1) * BK);    // issue next-tile loads first
        #pragma unroll
        for (int kk = 0; kk < BK; kk += 32) {
            bf16x8 af[4], bfr[4];
            #pragma unroll
            for (int m = 0; m < 4; ++m) {
                const int row = wm + m * 16 + fr;
                const int koff = ((((kk >> 3) + fq) ^ (row & 7)) << 3);
                af[m] = *(bf16x8*)&As[cur][row * BK + koff];
            }
            #pragma unroll
            for (int n = 0; n < 4; ++n) {
                const int row = wn + n * 16 + fr;
                const int koff = ((((kk >> 3) + fq) ^ (row & 7)) << 3);
                bfr[n] = *(bf16x8*)&Bs[cur][row * BK + koff];
            }
            #pragma unroll
            for (int m = 0; m < 4; ++m)
                #pragma unroll
                for (int n = 0; n < 4; ++n)
                    acc[m][n] = __builtin_amdgcn_mfma_f32_16x16x32_bf16(af[m], bfr[n], acc[m][n], 0, 0, 0);
        }
        __syncthreads();           // drains vmcnt (next stage) + lgkm, barrier
        cur ^= 1;
    }

    const bool diagblk = (bx == by);
    // exp transform in-place (+ exact diagonal mask)
    #pragma unroll
    for (int m = 0; m < 4; ++m)
        #pragma unroll
        for (int n = 0; n < 4; ++n)
            #pragma unroll
            for (int r = 0; r < 4; ++r) {
                const float e = __expf(2.f * acc[m][n][r]);
                const bool diag = diagblk && (wm + m * 16 + fq * 4 + r) == (wn + n * 16 + fr);
                acc[m][n][r] = diag ? 0.f : e;
            }
    // row sums: reduce over n-frags then over the 16 col-lanes
    #pragma unroll
    for (int m = 0; m < 4; ++m)
        #pragma unroll
        for (int r = 0; r < 4; ++r) {
            float v = acc[m][0][r] + acc[m][1][r] + acc[m][2][r] + acc[m][3][r];
            v += __shfl_xor(v, 1);
            v += __shfl_xor(v, 2);
            v += __shfl_xor(v, 4);
            v += __shfl_xor(v, 8);
            if (fr == 0) atomicAdd(&neg[rowA0 + wm + m * 16 + fq * 4 + r], v);
        }
    // mirrored column sums for off-diagonal blocks
    if (!diagblk) {
        #pragma unroll
        for (int n = 0; n < 4; ++n) {
            float v = 0.f;
            #pragma unroll
            for (int m = 0; m < 4; ++m)
                #pragma unroll
                for (int r = 0; r < 4; ++r) v += acc[m][n][r];
            v += __shfl_xor(v, 16);
            v += __shfl_xor(v, 32);
            if (fq == 0) atomicAdd(&neg[rowB0 + wn + n * 16 + fr], v);
        }
    }
}

// Kernel C: loss = log(2N) - log( sum_i pos[i] * (1/neg[i] + 1/neg[i+N]) )
__global__ __launch_bounds__(1024) void finish_kernel(const float* __restrict__ pos,
                                                      const float* __restrict__ neg,
                                                      float* __restrict__ out, int N) {
    float s = 0.f;
    for (int i = threadIdx.x; i < N; i += 1024)
        s += pos[i] * (1.f / neg[i] + 1.f / neg[i + N]);
    #pragma unroll
    for (int o = 32; o > 0; o >>= 1) s += __shfl_xor(s, o);
    __shared__ float red[16];
    const int wv = threadIdx.x >> 6;
    if ((threadIdx.x & 63) == 0) red[wv] = s;
    __syncthreads();
    if (threadIdx.x == 0) {
        float tot = 0.f;
        #pragma unroll
        for (int k = 0; k < 16; ++k) tot += red[k];
        out[0] = logf(2.f * (float)N) - logf(tot);
    }
}

extern "C" void kernel_launch(void* const* d_in, const int* in_sizes, int n_in,
                              void* d_out, int out_size, void* d_ws, size_t ws_size,
                              hipStream_t stream) {
    const float* y  = (const float*)d_in[0];
    const float* yh = (const float*)d_in[1];
    const int N  = in_sizes[0] / D;   // 4096
    const int N2 = 2 * N;             // 8192

    unsigned short* Yn = (unsigned short*)d_ws;                 // [2N][D] bf16, 8 MB
    const size_t yn_bytes = (size_t)N2 * D * sizeof(unsigned short);
    float* neg = (float*)((char*)d_ws + yn_bytes);              // [2N]
    float* pos = neg + N2;                                      // [N]
    float* out = (float*)d_out;

    hipMemsetAsync(neg, 0, N2 * sizeof(float), stream);
    prep_kernel<<<N, 128, 0, stream>>>(y, yh, Yn, pos, N);
    simgemm_kernel<<<NBLK, 256, 0, stream>>>(Yn, neg);
    finish_kernel<<<1, 1024, 0, stream>>>(pos, neg, out, N);
}